// Round 9
// baseline (1367.742 us; speedup 1.0000x reference)
//
#include <hip/hip_runtime.h>
#include <cmath>

// ---------------- problem constants ----------------
constexpr int BB = 4, SSQ = 1024, DD = 512, MM = 64, TTK = MM + SSQ; // 1088
constexpr int HH = 8, HD = DD / HH, WINDOW = 128;
constexpr int RROWS = BB * TTK;     // 4352
constexpr int OROWS = BB * SSQ;     // 4096
constexpr float LR_ = 1e-3f, WD_ = 1e-2f, MAXALR_ = 0.1f, EPS_ = 1e-8f;
constexpr float C2_ = 2.0f / (float)DD;
constexpr int VPAD = 200;
constexpr int SPLITK = 17;
constexpr int NBLK = 512;           // persistent grid (2 blocks/CU guaranteed co-resident)

typedef short  s16x8 __attribute__((ext_vector_type(8)));
typedef float  f32x4 __attribute__((ext_vector_type(4)));

__device__ __forceinline__ float b2f(unsigned short u) {
    union { unsigned int i; float f; } c; c.i = ((unsigned int)u) << 16; return c.f;
}
__device__ __forceinline__ unsigned short f2b(float f) {
    union { float f; unsigned int i; } c; c.f = f;
    unsigned int r = c.i + 0x7fffu + ((c.i >> 16) & 1u);   // RNE
    return (unsigned short)(r >> 16);
}
__device__ __forceinline__ float sigm(float x) { return 1.f / (1.f + __expf(-x)); }

__device__ __forceinline__ void gld16(const void* g, void* l) {
    __builtin_amdgcn_global_load_lds((const __attribute__((address_space(1))) unsigned int*)g,
                                     (__attribute__((address_space(3))) unsigned int*)l, 16, 0, 0);
}

// ---------------- device-scope grid barrier (all blocks resident by construction) ----------------
__device__ __forceinline__ void gsync(unsigned int* bar, unsigned int nb) {
    __syncthreads();
    if (threadIdx.x == 0) {
        __threadfence();                       // release: flush this XCD's writes
        unsigned int g = __hip_atomic_load(bar + 1, __ATOMIC_RELAXED, __HIP_MEMORY_SCOPE_AGENT);
        unsigned int a = __hip_atomic_fetch_add(bar, 1u, __ATOMIC_ACQ_REL, __HIP_MEMORY_SCOPE_AGENT);
        if (a == nb - 1) {
            __hip_atomic_store(bar, 0u, __ATOMIC_RELAXED, __HIP_MEMORY_SCOPE_AGENT);
            __hip_atomic_fetch_add(bar + 1, 1u, __ATOMIC_RELEASE, __HIP_MEMORY_SCOPE_AGENT);
        } else {
            while (__hip_atomic_load(bar + 1, __ATOMIC_ACQUIRE, __HIP_MEMORY_SCOPE_AGENT) == g)
                __builtin_amdgcn_s_sleep(8);
        }
        __threadfence();                       // acquire: invalidate stale lines
    }
    __syncthreads();
}

// ---------------- canonical bf16 MFMA GEMM body ----------------
// 512 threads / 8 waves, tile TMM x TNN, BK=64, double-buffered prefetch,
// XOR-swizzled LDS (pre-swizzled global source + swizzled ds_read).
// EPI: 0 bf16-out | 1 add-silu | 2 add-silu + write z | 3 pred/d2/dz2 | 4 dh1/dz1
//      5 f32-out | 6 f32 split-K partial store (out0 + bz*ld0)
struct GArgs {
    const unsigned short* A; const unsigned short* Bm;
    const float* bias;
    const unsigned short* aux0; const unsigned short* aux1;
    const float* wrow;
    void* out0; unsigned short* out1;
    unsigned short* outT; int tc0, tc1; float* gbOut;
    int M, N, K, lda, ld0, ld1;
};

template<int EPI, int TMM, int TNN, bool WTR, bool GBS>
__device__ __forceinline__ void mgemm_body(unsigned short* __restrict__ LB, float* __restrict__ gacc,
                                           int bx, int by, int bz, int gz, const GArgs& a, int tid)
{
    constexpr int WCOLS = TNN / 4;
    constexpr int NJ = WCOLS / 16;
    constexpr int NI = TMM / 32;
    constexpr int APASS = TMM / 64;
    constexpr int BPASS = TNN / 64;
    constexpr int ASZ = TMM * 64;
    constexpr int BSZ = TNN * 64;
    constexpr int TP  = TMM + 8;
    constexpr int CH  = TMM / 8;

    __syncthreads();                           // LB reuse guard (persistent loops)

    const int m0 = by * TMM, n0 = bx * TNN;
    const int ktiles = a.K >> 6;
    const int per = ktiles / gz;
    const int kt0 = bz * per, kt1 = kt0 + per;

    if (GBS && tid < 128) gacc[tid] = 0.f;

    const int r_ = tid >> 3, c_ = tid & 7;

    auto stage = [&](int buf, int kt) {
        const size_t kb = (size_t)kt * 64;
        const int sw = (c_ ^ (r_ & 7)) * 8;
#pragma unroll
        for (int p = 0; p < APASS; ++p) {
            int row = p * 64 + r_;
            gld16(a.A + (size_t)(m0 + row) * a.lda + kb + sw,
                  &LB[buf * ASZ + row * 64 + c_ * 8]);
        }
#pragma unroll
        for (int p = 0; p < BPASS; ++p) {
            int row = p * 64 + r_;
            gld16(a.Bm + (size_t)(n0 + row) * a.K + kb + sw,
                  &LB[2 * ASZ + buf * BSZ + row * 64 + c_ * 8]);
        }
    };

    f32x4 acc[NI][NJ];
#pragma unroll
    for (int i = 0; i < NI; ++i)
#pragma unroll
        for (int j = 0; j < NJ; ++j)
#pragma unroll
            for (int r = 0; r < 4; ++r) acc[i][j][r] = 0.f;

    const int lane = tid & 63, wv = tid >> 6;
    const int wr = wv & 1, wc = wv >> 1;
    const int fr = lane & 15, fg = lane >> 4;

    stage(0, kt0);
    int cur = 0;
    for (int kt = kt0; kt < kt1; ++kt) {
        __syncthreads();
        if (kt + 1 < kt1) stage(cur ^ 1, kt + 1);
#pragma unroll
        for (int ks = 0; ks < 2; ++ks) {
            s16x8 av[NI], bv[NJ];
#pragma unroll
            for (int i = 0; i < NI; ++i) {
                const int arow = wr * (TMM / 2) + i * 16 + fr;
                av[i] = *(const s16x8*)&LB[cur * ASZ + arow * 64 + (((ks * 4 + fg) ^ (arow & 7)) * 8)];
            }
#pragma unroll
            for (int j = 0; j < NJ; ++j) {
                const int brow = wc * WCOLS + j * 16 + fr;
                bv[j] = *(const s16x8*)&LB[2 * ASZ + cur * BSZ + brow * 64 + (((ks * 4 + fg) ^ (brow & 7)) * 8)];
            }
#pragma unroll
            for (int i = 0; i < NI; ++i)
#pragma unroll
                for (int j = 0; j < NJ; ++j)
                    acc[i][j] = __builtin_amdgcn_mfma_f32_16x16x32_bf16(av[i], bv[j], acc[i][j], 0, 0, 0);
        }
        cur ^= 1;
    }
    __syncthreads();

    const bool wtr_blk = WTR && (n0 >= a.tc0) && (n0 < a.tc1);
    unsigned short* TL = LB;

    float gsum[NJ];
#pragma unroll
    for (int j = 0; j < NJ; ++j) gsum[j] = 0.f;

#pragma unroll
    for (int j = 0; j < NJ; ++j) {
        const int col = n0 + wc * WCOLS + j * 16 + fr;
        const float bj = (EPI == 6 || a.bias == nullptr) ? 0.f : a.bias[col];
#pragma unroll
        for (int i = 0; i < NI; ++i) {
            const int rowb = m0 + wr * (TMM / 2) + i * 16 + fg * 4;
#pragma unroll
            for (int r = 0; r < 4; ++r) {
                const int row = rowb + r;
                const size_t off  = (size_t)row * a.N + col;
                const size_t off0 = (size_t)row * a.ld0 + col;
                const size_t off1 = (size_t)row * a.ld1 + col;
                float val = acc[i][j][r] + bj;
                float tv = val;
                if constexpr (EPI == 0) {
                    ((unsigned short*)a.out0)[off] = f2b(val);
                } else if constexpr (EPI == 1 || EPI == 2) {
                    float base = b2f(a.aux0[off0]);
                    float h = base + val * sigm(val);
                    ((unsigned short*)a.out0)[off] = f2b(h);
                    if constexpr (EPI == 2) a.out1[off] = f2b(val);
                    tv = h;
                } else if constexpr (EPI == 3) {
                    float h1 = b2f(a.aux0[off0]);
                    float pred = h1 + val * sigm(val);
                    float vv = b2f(a.aux1[off1]);
                    float d2 = C2_ * a.wrow[row] * (pred - vv);
                    float s = sigm(val);
                    float dz2 = d2 * (s * (1.f + val * (1.f - s)));
                    ((unsigned short*)a.out0)[off] = f2b(d2);
                    a.out1[off] = f2b(dz2);
                    tv = dz2;
                } else if constexpr (EPI == 4) {
                    float dh = val + b2f(a.aux0[off0]);
                    float z1 = b2f(a.aux1[off1]);
                    float s = sigm(z1);
                    float dz1v = dh * (s * (1.f + z1 * (1.f - s)));
                    ((unsigned short*)a.out0)[off] = f2b(dz1v);
                    tv = dz1v;
                } else if constexpr (EPI == 5) {
                    ((float*)a.out0)[off] = val;
                } else {
                    ((float*)a.out0)[(size_t)bz * a.ld0 + off] = val;
                }
                if (wtr_blk)
                    TL[(size_t)(col - n0) * TP + (row - m0)] = f2b(tv);
                if constexpr (GBS) gsum[j] += tv;
            }
        }
    }

    if constexpr (GBS) {
#pragma unroll
        for (int j = 0; j < NJ; ++j) {
            float s = gsum[j];
            s += __shfl_xor(s, 16);
            s += __shfl_xor(s, 32);
            if (lane < 16) atomicAdd(&gacc[wc * WCOLS + j * 16 + fr], s);
        }
    }

    if (wtr_blk || GBS) {
        __syncthreads();
        if (wtr_blk) {
            for (int idx = tid; idx < TNN * CH; idx += 512) {
                int c = idx / CH, ch = idx % CH;
                s16x8 v = *(const s16x8*)&TL[(size_t)c * TP + ch * 8];
                *(s16x8*)&a.outT[(size_t)(n0 - a.tc0 + c) * a.M + m0 + ch * 8] = v;
            }
        }
        if (GBS && tid < TNN) atomicAdd(a.gbOut + n0 + tid, gacc[tid]);
    }
}

// ---------------- adamw update + transpose body (tid<256 active) ----------------
__device__ __forceinline__ void adamw_body(unsigned short* LBraw,
                                           const float* W, const float* gWp,
                                           unsigned short* dstBase, const float* pb,
                                           const float* gB, float* bnOut,
                                           int bx, int by, int z, int tid) {
    __syncthreads();                           // LB reuse guard
    if (z == 2) {
        if (tid < 256) {
            int idx = (by * 8 + bx) * 256 + tid;
            if (idx < 2 * DD) {
                float gg = gB[idx];
                bnOut[idx] = pb[idx] * (1.f - LR_ * WD_) - LR_ * gg / (fabsf(gg) + EPS_);
            }
        }
        return;
    }
    auto t = (unsigned short (*)[65])LBraw;
    const float* src = W + (size_t)z * DD * DD;
    unsigned short* dst = dstBase + (size_t)z * DD * DD;
    int r0 = by * 64, c0 = bx * 64;
    int lr = tid >> 4, lc = (tid & 15) * 4;
    if (tid < 256) {
#pragma unroll
        for (int rr = 0; rr < 64; rr += 16) {
            size_t base = (size_t)(r0 + lr + rr) * 512 + c0 + lc;
            float4 v = *(const float4*)(src + base);
            float gx = 0.f, gy = 0.f, gz2 = 0.f, gw = 0.f;
            for (int zz = 0; zz < SPLITK; ++zz) {
                const float4 p4 = *(const float4*)(gWp + ((size_t)zz * 2 + z) * DD * DD + base);
                gx += p4.x; gy += p4.y; gz2 += p4.z; gw += p4.w;
            }
            t[lr + rr][lc]     = f2b(v.x * (1.f - LR_ * WD_) - LR_ * gx / (fabsf(gx) + EPS_));
            t[lr + rr][lc + 1] = f2b(v.y * (1.f - LR_ * WD_) - LR_ * gy / (fabsf(gy) + EPS_));
            t[lr + rr][lc + 2] = f2b(v.z * (1.f - LR_ * WD_) - LR_ * gz2 / (fabsf(gz2) + EPS_));
            t[lr + rr][lc + 3] = f2b(v.w * (1.f - LR_ * WD_) - LR_ * gw / (fabsf(gw) + EPS_));
        }
    }
    __syncthreads();
    if (tid < 256) {
#pragma unroll
        for (int cc = 0; cc < 64; cc += 16) {
            int c = lr + cc;
            ushort4 o; o.x = t[lc][c]; o.y = t[lc + 1][c]; o.z = t[lc + 2][c]; o.w = t[lc + 3][c];
            *(ushort4*)(dst + (size_t)(c0 + c) * 512 + r0 + lc) = o;
        }
    }
}

// ---------------- MFMA sliding-window attention body (tid<256 active) ----------------
__device__ __forceinline__ void swa_body(unsigned short* LB, int qt, int h, int b,
                                         const unsigned short* AQ, unsigned short* O, int tid) {
    unsigned short* Qs = LB;                   // 64*64
    unsigned short* KP = LB + 4096;            // 192*64, then P 64x192
    unsigned short* Vt = LB + 16384;           // 64*VPAD
    __syncthreads();                           // LB reuse guard

    const int i0 = MM + qt * 64;
    const int jbase = i0 - 128;
    const int lane = tid & 63, w = tid >> 6;
    const int g = lane >> 4, fl = lane & 15;
    const int qA = w * 16 + fl;
    const int swzA = qA & 7;
    const int kmin = (i0 < 128) ? (128 - i0) : 0;

    if (tid < 256) {
        const int r_ = tid >> 3, c_ = tid & 7;
#pragma unroll
        for (int rd = 0; rd < 2; ++rd) {
            int r = rd * 32 + r_;
            const unsigned short* src = AQ + ((size_t)(b * TTK + i0 + r)) * 1536 + h * HD
                                        + ((c_ ^ (r & 7)) * 8);
            gld16(src, &Qs[rd * 2048 + tid * 8]);
        }
#pragma unroll
        for (int rd = 0; rd < 6; ++rd) {
            int r = rd * 32 + r_;
            int j = jbase + r; if (j < 0) j = 0;
            const unsigned short* src = AQ + ((size_t)(b * TTK + j)) * 1536 + 512 + h * HD
                                        + ((c_ ^ (r & 7)) * 8);
            gld16(src, &KP[rd * 2048 + tid * 8]);
        }
#pragma unroll
        for (int rd = 0; rd < 6; ++rd) {
            int r = rd * 32 + r_;
            int j = jbase + r; if (j < 0) j = 0;
            const s16x8 vv = *(const s16x8*)(AQ + ((size_t)(b * TTK + j)) * 1536 + 1024 + h * HD + c_ * 8);
#pragma unroll
            for (int i = 0; i < 8; ++i)
                Vt[(c_ * 8 + i) * VPAD + r] = (unsigned short)vv[i];
        }
    }
    __syncthreads();

    f32x4 sc[12];
    float mx[4], ls[4];
    if (tid < 256) {
#pragma unroll
        for (int t = 0; t < 12; ++t) { sc[t][0] = 0.f; sc[t][1] = 0.f; sc[t][2] = 0.f; sc[t][3] = 0.f; }
#pragma unroll
        for (int ks = 0; ks < 2; ++ks) {
            s16x8 af = *(const s16x8*)&Qs[qA * 64 + (((4 * ks + g) ^ swzA) * 8)];
#pragma unroll
            for (int t = 0; t < 12; ++t) {
                int jn = t * 16 + fl;
                s16x8 bf = *(const s16x8*)&KP[jn * 64 + (((4 * ks + g) ^ (jn & 7)) * 8)];
                sc[t] = __builtin_amdgcn_mfma_f32_16x16x32_bf16(af, bf, sc[t], 0, 0, 0);
            }
        }
#pragma unroll
        for (int r = 0; r < 4; ++r) mx[r] = -1e30f;
#pragma unroll
        for (int t = 0; t < 12; ++t) {
            int kk = t * 16 + fl;
#pragma unroll
            for (int r = 0; r < 4; ++r) {
                int qb = w * 16 + g * 4 + r;
                bool m = (kk > qb) && (kk <= qb + 128) && (kk >= kmin);
                float v = m ? sc[t][r] * 0.125f : -1e30f;
                sc[t][r] = v;
                mx[r] = fmaxf(mx[r], v);
            }
        }
#pragma unroll
        for (int r = 0; r < 4; ++r) {
            mx[r] = fmaxf(mx[r], __shfl_xor(mx[r], 1));
            mx[r] = fmaxf(mx[r], __shfl_xor(mx[r], 2));
            mx[r] = fmaxf(mx[r], __shfl_xor(mx[r], 4));
            mx[r] = fmaxf(mx[r], __shfl_xor(mx[r], 8));
        }
#pragma unroll
        for (int r = 0; r < 4; ++r) ls[r] = 0.f;
#pragma unroll
        for (int t = 0; t < 12; ++t) {
#pragma unroll
            for (int r = 0; r < 4; ++r) {
                float p = __expf(sc[t][r] - mx[r]);
                sc[t][r] = p;
                ls[r] += p;
            }
        }
#pragma unroll
        for (int r = 0; r < 4; ++r) {
            ls[r] += __shfl_xor(ls[r], 1);
            ls[r] += __shfl_xor(ls[r], 2);
            ls[r] += __shfl_xor(ls[r], 4);
            ls[r] += __shfl_xor(ls[r], 8);
        }
    }
    __syncthreads();                           // all waves done reading K tile

    if (tid < 256) {
#pragma unroll
        for (int t = 0; t < 12; ++t) {
            int kk = t * 16 + fl;
#pragma unroll
            for (int r = 0; r < 4; ++r) {
                int qb = w * 16 + g * 4 + r;
                int ch = (kk >> 3) ^ (qb & 7);
                KP[qb * 192 + ch * 8 + (kk & 7)] = f2b(sc[t][r]);
            }
        }
    }
    __syncthreads();

    if (tid < 256) {
        f32x4 oacc[4];
#pragma unroll
        for (int dt = 0; dt < 4; ++dt) { oacc[dt][0] = 0.f; oacc[dt][1] = 0.f; oacc[dt][2] = 0.f; oacc[dt][3] = 0.f; }
#pragma unroll
        for (int js = 0; js < 6; ++js) {
            s16x8 pa = *(const s16x8*)&KP[qA * 192 + (((js * 4 + g) ^ swzA) * 8)];
#pragma unroll
            for (int dt = 0; dt < 4; ++dt) {
                s16x8 bv = *(const s16x8*)&Vt[(dt * 16 + fl) * VPAD + js * 32 + g * 8];
                oacc[dt] = __builtin_amdgcn_mfma_f32_16x16x32_bf16(pa, bv, oacc[dt], 0, 0, 0);
            }
        }
        float inv[4];
#pragma unroll
        for (int r = 0; r < 4; ++r) inv[r] = 1.f / ls[r];
#pragma unroll
        for (int dt = 0; dt < 4; ++dt) {
#pragma unroll
            for (int r = 0; r < 4; ++r) {
                int qb = w * 16 + g * 4 + r;
                int srow = qt * 64 + qb;
                int d = dt * 16 + fl;
                O[((size_t)b * SSQ + srow) * DD + h * HD + d] = f2b(oacc[dt][r] * inv[r]);
            }
        }
    }
}

// ---------------- the persistent pipeline ----------------
struct MPArgs {
    GArgs qkv, l1, l2, g1, dz, g0, r1, r2, sp, op;
    const unsigned short* aq; unsigned short* o;      // swa in/out
    const float* lmmW; const float* gWp; unsigned short* WT10;
    const float* lmmb; const float* gb; float* bn;
    unsigned int* bar;
};

__global__ __launch_bounds__(512, 4) void megapipe(MPArgs M) {
    // LDS union: mgemm (<=48KB) | swa Qs+KP+Vt (57.0KB) | adamw t[64][65]
    __shared__ __align__(16) unsigned short LB[29184];
    __shared__ float gacc[128];
    const int tid = threadIdx.x;
    const unsigned int nb = gridDim.x;
    unsigned int* bar = M.bar;

    for (unsigned int t = blockIdx.x; t < 816; t += nb)                     // P1 qkv proj
        mgemm_body<0, 64, 128, true, false>(LB, gacc, t % 12, t / 12, 0, 1, M.qkv, tid);
    gsync(bar, nb);
    for (unsigned int t = blockIdx.x; t < 544; t += nb)                     // P2 lmm fwd 1
        mgemm_body<2, 64, 64, true, false>(LB, gacc, t & 7, t >> 3, 0, 1, M.l1, tid);
    gsync(bar, nb);
    for (unsigned int t = blockIdx.x; t < 544; t += nb)                     // P3 pred/d2/dz2
        mgemm_body<3, 64, 64, true, true>(LB, gacc, t & 7, t >> 3, 0, 1, M.l2, tid);
    gsync(bar, nb);
    for (unsigned int t = blockIdx.x; t < 1088; t += nb) {                  // P4 gW1 || dz1
        if (t < 544) { int bz = t >> 5, rem = t & 31;
            mgemm_body<6, 64, 128, false, false>(LB, gacc, rem & 3, rem >> 2, bz, SPLITK, M.g1, tid);
        } else { unsigned int u = t - 544;
            mgemm_body<4, 64, 64, true, true>(LB, gacc, u & 7, u >> 3, 0, 1, M.dz, tid);
        }
    }
    gsync(bar, nb);
    for (unsigned int t = blockIdx.x; t < 544; t += nb) {                   // P5 gW0
        int bz = t >> 5, rem = t & 31;
        mgemm_body<6, 64, 128, false, false>(LB, gacc, rem & 3, rem >> 2, bz, SPLITK, M.g0, tid);
    }
    gsync(bar, nb);
    for (unsigned int t = blockIdx.x; t < 192; t += nb)                     // P6 adamw
        adamw_body(LB, M.lmmW, M.gWp, M.WT10, M.lmmb, M.gb, M.bn,
                   (int)(t & 7), (int)((t >> 3) & 7), (int)(t >> 6), tid);
    gsync(bar, nb);
    for (unsigned int t = blockIdx.x; t < 544; t += nb)                     // P7 retrieval 1
        mgemm_body<1, 64, 64, false, false>(LB, gacc, t & 7, t >> 3, 0, 1, M.r1, tid);
    gsync(bar, nb);
    for (unsigned int t = blockIdx.x; t < 544; t += nb)                     // P8 retrieval 2
        mgemm_body<1, 64, 64, false, false>(LB, gacc, t & 7, t >> 3, 0, 1, M.r2, tid);
    gsync(bar, nb);
    for (unsigned int t = blockIdx.x; t < 816; t += nb)                     // P9 swa proj
        mgemm_body<0, 64, 128, false, false>(LB, gacc, t % 12, t / 12, 0, 1, M.sp, tid);
    gsync(bar, nb);
    for (unsigned int t = blockIdx.x; t < 512; t += nb)                     // P10 attention
        swa_body(LB, (int)(t & 15), (int)((t >> 4) & 7), (int)(t >> 7), M.aq, M.o, tid);
    gsync(bar, nb);
    for (unsigned int t = blockIdx.x; t < 512; t += nb)                     // P11 out proj
        mgemm_body<5, 64, 64, false, false>(LB, gacc, t & 7, t >> 3, 0, 1, M.op, tid);
}

// ---------------- mega setup: weight transposes + xm/lr rows + bias concat + barrier init ----------------
struct TXP { const float* s[10]; unsigned short* d[10]; };
__global__ __launch_bounds__(256) void mega_setup(TXP p,
    const float* __restrict__ x, const float* __restrict__ meta, unsigned short* __restrict__ xm,
    const float* __restrict__ Wlr, const float* __restrict__ blr, float* __restrict__ w,
    const float* bq, const float* bk, const float* bv,
    const float* sb, float* cb1, float* cb2, float* gb, unsigned int* bar)
{
    const int bid = blockIdx.x, tid = threadIdx.x;
    if (bid < 640) {
        __shared__ unsigned short t[64][65];
        int z = bid >> 6;
        const float* src = p.s[z];
        unsigned short* dst = p.d[z];
        int r0 = ((bid >> 3) & 7) * 64, c0 = (bid & 7) * 64;
        int lr = tid >> 4, lc = (tid & 15) * 4;
        if (z == 9) {
#pragma unroll
            for (int rr = 0; rr < 64; rr += 16) {
                size_t base = (size_t)(r0 + lr + rr) * 512 + c0 + lc;
                float4 v = *(const float4*)(src + base);
                ushort4 o; o.x = f2b(v.x); o.y = f2b(v.y); o.z = f2b(v.z); o.w = f2b(v.w);
                *(ushort4*)(dst + base) = o;
            }
            return;
        }
#pragma unroll
        for (int rr = 0; rr < 64; rr += 16) {
            float4 v = *(const float4*)(src + (size_t)(r0 + lr + rr) * 512 + c0 + lc);
            t[lr + rr][lc] = f2b(v.x); t[lr + rr][lc + 1] = f2b(v.y);
            t[lr + rr][lc + 2] = f2b(v.z); t[lr + rr][lc + 3] = f2b(v.w);
        }
        __syncthreads();
#pragma unroll
        for (int cc = 0; cc < 64; cc += 16) {
            int c = lr + cc;
            ushort4 o; o.x = t[lc][c]; o.y = t[lc + 1][c]; o.z = t[lc + 2][c]; o.w = t[lc + 3][c];
            *(ushort4*)(dst + (size_t)(c0 + c) * 512 + r0 + lc) = o;
        }
        return;
    }
    if (bid < 640 + RROWS) {
        __shared__ float sm[4];
        int row = bid - 640;
        int b = row / TTK, tt = row % TTK;
        const float* src = (tt < MM) ? meta + (size_t)tt * DD
                                     : x + ((size_t)b * SSQ + (tt - MM)) * DD;
        float x0 = src[tid], x1 = src[tid + 256];
        unsigned short* dst = xm + (size_t)row * DD;
        dst[tid] = f2b(x0); dst[tid + 256] = f2b(x1);
        float s = x0 * Wlr[tid] + x1 * Wlr[tid + 256];
        for (int o2 = 32; o2; o2 >>= 1) s += __shfl_down(s, o2);
        if ((tid & 63) == 0) sm[tid >> 6] = s;
        __syncthreads();
        if (tid == 0) w[row] = MAXALR_ / (1.f + __expf(-(sm[0] + sm[1] + sm[2] + sm[3] + blr[0])));
        return;
    }
    int i = (bid - 640 - RROWS) * 256 + tid;
    if (i < 1536) {
        float v = (i < 512) ? bq[i] : (i < 1024) ? bk[i - 512] : bv[i - 1024];
        cb1[i] = v; cb2[i] = sb[i];
    } else if (i < 2560) {
        gb[i - 1536] = 0.f;
    } else if (i < 2562) {
        bar[i - 2560] = 0u;
    }
}

// ---------------- launch ----------------
extern "C" void kernel_launch(void* const* d_in, const int* in_sizes, int n_in,
                              void* d_out, int out_size, void* d_ws, size_t ws_size,
                              hipStream_t stream) {
    const float* x    = (const float*)d_in[0];
    const float* meta = (const float*)d_in[1];
    const float* lmmW = (const float*)d_in[2];
    const float* lmmb = (const float*)d_in[3];
    const float* Wq   = (const float*)d_in[4];
    const float* bq   = (const float*)d_in[5];
    const float* Wk   = (const float*)d_in[6];
    const float* bk   = (const float*)d_in[7];
    const float* Wv   = (const float*)d_in[8];
    const float* bv   = (const float*)d_in[9];
    const float* Wlr  = (const float*)d_in[10];
    const float* blr  = (const float*)d_in[11];
    const float* swaW = (const float*)d_in[12];
    const float* swab = (const float*)d_in[13];
    float* out = (float*)d_out;
    (void)in_sizes; (void)n_in; (void)out_size; (void)ws_size;

    char* wsb = (char*)d_ws;
    size_t off = 0;
    auto alloc = [&](size_t bytes) -> void* {
        void* p = wsb + off; off = (off + bytes + 255) & ~(size_t)255; return p;
    };
    const size_t BIGE = (size_t)RROWS * DD;
    unsigned short* qkv  = (unsigned short*)alloc((size_t)RROWS * 1536 * 2);  // q|k|v, later aq|ak|av
    unsigned short* xm   = (unsigned short*)alloc(BIGE * 2);
    unsigned short* h1   = (unsigned short*)alloc(BIGE * 2);
    unsigned short* z1   = (unsigned short*)alloc(BIGE * 2);
    unsigned short* d2   = (unsigned short*)alloc(BIGE * 2);
    unsigned short* dz2  = (unsigned short*)alloc(BIGE * 2);
    unsigned short* dz1  = (unsigned short*)alloc(BIGE * 2);
    unsigned short* h1r  = (unsigned short*)alloc(BIGE * 2);
    unsigned short* retr = (unsigned short*)alloc(BIGE * 2);
    unsigned short* o    = (unsigned short*)alloc((size_t)OROWS * DD * 2);
    unsigned short* kT   = (unsigned short*)alloc(BIGE * 2);
    unsigned short* h1T  = (unsigned short*)alloc(BIGE * 2);
    unsigned short* dz2T = (unsigned short*)alloc(BIGE * 2);
    unsigned short* dz1T = (unsigned short*)alloc(BIGE * 2);
    unsigned short* Wt   = (unsigned short*)alloc((size_t)12 * DD * DD * 2);
    float* gWp  = (float*)alloc((size_t)SPLITK * 2 * DD * DD * 4);
    float* w    = (float*)alloc((size_t)RROWS * 4);
    float* gb   = (float*)alloc(1024 * 4);
    float* bn   = (float*)alloc(1024 * 4);
    float* cbQ  = (float*)alloc(1536 * 4);
    float* cbS  = (float*)alloc(1536 * 4);
    unsigned int* bar = (unsigned int*)alloc(256);
    auto WT = [&](int i) { return Wt + (size_t)i * DD * DD; };

    TXP tp{};
    tp.s[0] = Wq;             tp.d[0] = WT(0);
    tp.s[1] = Wk;             tp.d[1] = WT(1);
    tp.s[2] = Wv;             tp.d[2] = WT(2);
    tp.s[3] = lmmW;           tp.d[3] = WT(3);
    tp.s[4] = lmmW + DD * DD; tp.d[4] = WT(4);
    tp.s[5] = swaW + 0 * DD * DD; tp.d[5] = WT(5);
    tp.s[6] = swaW + 1 * DD * DD; tp.d[6] = WT(6);
    tp.s[7] = swaW + 2 * DD * DD; tp.d[7] = WT(7);
    tp.s[8] = swaW + 3 * DD * DD; tp.d[8] = WT(8);
    tp.s[9] = lmmW + DD * DD; tp.d[9] = WT(9);
    mega_setup<<<640 + RROWS + 11, 256, 0, stream>>>(tp, x, meta, xm, Wlr, blr, w,
                                                     bq, bk, bv, swab, cbQ, cbS, gb, bar);

    auto ga = [](const unsigned short* A, const unsigned short* Bm, const float* bias,
                 const unsigned short* a0, const unsigned short* a1, const float* wr,
                 void* o0, unsigned short* o1, unsigned short* oT, int t0, int t1, float* gbo,
                 int M, int N, int K, int lda, int l0, int l1) {
        GArgs g{A, Bm, bias, a0, a1, wr, o0, o1, oT, t0, t1, gbo, M, N, K, lda, l0, l1};
        return g;
    };

    MPArgs M{};
    M.qkv = ga(xm, WT(0), cbQ, nullptr, nullptr, nullptr, qkv, nullptr, kT, 512, 1024, nullptr,
               RROWS, 1536, DD, DD, 0, 0);
    M.l1  = ga(qkv + 512, WT(3), lmmb, qkv + 512, nullptr, nullptr, h1, z1, h1T, 0, 512, nullptr,
               RROWS, DD, DD, 1536, 1536, 0);
    M.l2  = ga(h1, WT(4), lmmb + DD, h1, qkv + 1024, w, d2, dz2, dz2T, 0, 512, gb + DD,
               RROWS, DD, DD, DD, DD, 1536);
    M.g1  = ga(h1T, dz2T, nullptr, nullptr, nullptr, nullptr, gWp + DD * DD, nullptr, nullptr, 0, 0, nullptr,
               DD, DD, RROWS, RROWS, 2 * DD * DD, 0);
    M.dz  = ga(dz2, WT(9), nullptr, d2, z1, nullptr, dz1, nullptr, dz1T, 0, 512, gb,
               RROWS, DD, DD, DD, DD, DD);
    M.g0  = ga(kT, dz1T, nullptr, nullptr, nullptr, nullptr, gWp, nullptr, nullptr, 0, 0, nullptr,
               DD, DD, RROWS, RROWS, 2 * DD * DD, 0);
    M.r1  = ga(qkv, WT(10), bn, qkv, nullptr, nullptr, h1r, nullptr, nullptr, 0, 0, nullptr,
               RROWS, DD, DD, 1536, 1536, 0);
    M.r2  = ga(h1r, WT(11), bn + DD, h1r, nullptr, nullptr, retr, nullptr, nullptr, 0, 0, nullptr,
               RROWS, DD, DD, DD, DD, 0);
    M.sp  = ga(retr, WT(5), cbS, nullptr, nullptr, nullptr, qkv, nullptr, nullptr, 0, 0, nullptr,
               RROWS, 1536, DD, DD, 0, 0);
    M.op  = ga(o, WT(8), swab + 3 * DD, nullptr, nullptr, nullptr, out, nullptr, nullptr, 0, 0, nullptr,
               OROWS, DD, DD, DD, 0, 0);
    M.aq = qkv; M.o = o;
    M.lmmW = lmmW; M.gWp = gWp; M.WT10 = WT(10);
    M.lmmb = lmmb; M.gb = gb; M.bn = bn;
    M.bar = bar;

    megapipe<<<NBLK, 512, 0, stream>>>(M);
}

// Round 10
// 235.563 us; speedup vs baseline: 5.8063x; 5.8063x over previous
//
#include <hip/hip_runtime.h>
#include <cmath>

// ---------------- problem constants ----------------
constexpr int BB = 4, SSQ = 1024, DD = 512, MM = 64, TTK = MM + SSQ; // 1088
constexpr int HH = 8, HD = DD / HH, WINDOW = 128;
constexpr int RROWS = BB * TTK;     // 4352
constexpr int OROWS = BB * SSQ;     // 4096
constexpr float LR_ = 1e-3f, WD_ = 1e-2f, MAXALR_ = 0.1f, EPS_ = 1e-8f;
constexpr float C2_ = 2.0f / (float)DD;
constexpr int VPAD = 200;
constexpr int SPLITK = 17;

typedef short  s16x8 __attribute__((ext_vector_type(8)));
typedef float  f32x4 __attribute__((ext_vector_type(4)));

__device__ __forceinline__ float b2f(unsigned short u) {
    union { unsigned int i; float f; } c; c.i = ((unsigned int)u) << 16; return c.f;
}
__device__ __forceinline__ unsigned short f2b(float f) {
    union { float f; unsigned int i; } c; c.f = f;
    unsigned int r = c.i + 0x7fffu + ((c.i >> 16) & 1u);   // RNE
    return (unsigned short)(r >> 16);
}
__device__ __forceinline__ float sigm(float x) { return 1.f / (1.f + __expf(-x)); }

__device__ __forceinline__ void gld16(const void* g, void* l) {
    __builtin_amdgcn_global_load_lds((const __attribute__((address_space(1))) unsigned int*)g,
                                     (__attribute__((address_space(3))) unsigned int*)l, 16, 0, 0);
}

// ---------------- canonical bf16 MFMA GEMM body ----------------
// 512 threads / 8 waves (2 row-halves x 4 col-quarters), tile 64x64, BK=64.
// TRIPLE-buffered K-pipeline with counted vmcnt: per iteration
//   s_waitcnt vmcnt(2); s_barrier;  -> current tile's 2 loads done, next tile's
//   2 loads STAY IN FLIGHT across the barrier (T4); then stage tile kt+2 into
//   the buffer freed at kt-1 (all waves crossed that barrier -> overwrite safe).
// XOR-swizzled LDS (pre-swizzled global source + swizzled ds_read).
// EPI: 0 bf16-out | 1 add-silu | 2 add-silu + write z | 3 pred/d2/dz2 | 4 dh1/dz1
//      5 f32-out | 6 f32 split-K partial store (out0 + bz*ld0)
struct GArgs {
    const unsigned short* A; const unsigned short* Bm;
    const float* bias;
    const unsigned short* aux0; const unsigned short* aux1;
    const float* wrow;
    void* out0; unsigned short* out1;
    unsigned short* outT; int tc0, tc1; float* gbOut;
    int M, N, K, lda, ld0, ld1;
};

constexpr int ASZ = 64 * 64;       // one A/B buffer (shorts)
constexpr int LBSZ = 6 * ASZ;      // 3 x (A + B) = 48 KB

template<int EPI, bool WTR, bool GBS>
__device__ __forceinline__ void mgemm_body(unsigned short* __restrict__ LB, float* __restrict__ gacc,
                                           int bx, int by, int bz, int gz, const GArgs& a, int tid)
{
    constexpr int TP = 72;          // transposed-tile stride
    const int m0 = by * 64, n0 = bx * 64;
    const int ktiles = a.K >> 6;
    const int per = ktiles / gz;
    const int kt0 = bz * per;
    const int nt = per;

    if (GBS && tid < 128) gacc[tid] = 0.f;

    const int r_ = tid >> 3, c_ = tid & 7;     // 64 rows x 8 chunks

    auto stage = [&](int buf, int kt) {        // 2 loads/thread (LPS = 2)
        const size_t kb = (size_t)kt * 64;
        const int sw = (c_ ^ (r_ & 7)) * 8;    // pre-swizzled source chunk
        gld16(a.A + (size_t)(m0 + r_) * a.lda + kb + sw,
              &LB[buf * 2 * ASZ + r_ * 64 + c_ * 8]);
        gld16(a.Bm + (size_t)(n0 + r_) * a.K + kb + sw,
              &LB[buf * 2 * ASZ + ASZ + r_ * 64 + c_ * 8]);
    };

    f32x4 acc[2];
    acc[0][0] = 0.f; acc[0][1] = 0.f; acc[0][2] = 0.f; acc[0][3] = 0.f;
    acc[1] = acc[0];

    const int lane = tid & 63, wv = tid >> 6;
    const int wr = wv & 1, wc = wv >> 1;       // 2 row-halves x 4 col-quarters
    const int fr = lane & 15, fg = lane >> 4;

    stage(0, kt0);
    if (nt > 1) stage(1, kt0 + 1);
    for (int it = 0; it < nt; ++it) {
        if (it + 1 < nt) asm volatile("s_waitcnt vmcnt(2)" ::: "memory");
        else             asm volatile("s_waitcnt vmcnt(0)" ::: "memory");
        __builtin_amdgcn_s_barrier();
        if (it + 2 < nt) stage((it + 2) % 3, kt0 + it + 2);
        const int cb = (it % 3) * 2 * ASZ;
#pragma unroll
        for (int ks = 0; ks < 2; ++ks) {
            s16x8 av[2], bv;
#pragma unroll
            for (int i = 0; i < 2; ++i) {
                const int arow = wr * 32 + i * 16 + fr;
                av[i] = *(const s16x8*)&LB[cb + arow * 64 + (((ks * 4 + fg) ^ (arow & 7)) * 8)];
            }
            const int brow = wc * 16 + fr;
            bv = *(const s16x8*)&LB[cb + ASZ + brow * 64 + (((ks * 4 + fg) ^ (brow & 7)) * 8)];
#pragma unroll
            for (int i = 0; i < 2; ++i)
                acc[i] = __builtin_amdgcn_mfma_f32_16x16x32_bf16(av[i], bv, acc[i], 0, 0, 0);
        }
    }
    __syncthreads();                           // full drain before LB reuse as TL

    const bool wtr_blk = WTR && (n0 >= a.tc0) && (n0 < a.tc1);
    unsigned short* TL = LB;                   // [64][TP] transposed tile

    float gsum = 0.f;

    // epilogue: C/D layout col=lane&15, row=(lane>>4)*4+reg
    {
        const int col = n0 + wc * 16 + fr;
        const float bj = (EPI == 6 || a.bias == nullptr) ? 0.f : a.bias[col];
#pragma unroll
        for (int i = 0; i < 2; ++i) {
            const int rowb = m0 + wr * 32 + i * 16 + fg * 4;
#pragma unroll
            for (int r = 0; r < 4; ++r) {
                const int row = rowb + r;
                const size_t off  = (size_t)row * a.N + col;
                const size_t off0 = (size_t)row * a.ld0 + col;
                const size_t off1 = (size_t)row * a.ld1 + col;
                float val = acc[i][r] + bj;
                float tv = val;
                if constexpr (EPI == 0) {
                    ((unsigned short*)a.out0)[off] = f2b(val);
                } else if constexpr (EPI == 1 || EPI == 2) {
                    float base = b2f(a.aux0[off0]);
                    float h = base + val * sigm(val);
                    ((unsigned short*)a.out0)[off] = f2b(h);
                    if constexpr (EPI == 2) a.out1[off] = f2b(val);
                    tv = h;
                } else if constexpr (EPI == 3) {
                    float h1 = b2f(a.aux0[off0]);
                    float pred = h1 + val * sigm(val);
                    float vv = b2f(a.aux1[off1]);
                    float d2 = C2_ * a.wrow[row] * (pred - vv);
                    float s = sigm(val);
                    float dz2 = d2 * (s * (1.f + val * (1.f - s)));
                    ((unsigned short*)a.out0)[off] = f2b(d2);
                    a.out1[off] = f2b(dz2);
                    tv = dz2;
                } else if constexpr (EPI == 4) {
                    float dh = val + b2f(a.aux0[off0]);
                    float z1 = b2f(a.aux1[off1]);
                    float s = sigm(z1);
                    float dz1v = dh * (s * (1.f + z1 * (1.f - s)));
                    ((unsigned short*)a.out0)[off] = f2b(dz1v);
                    tv = dz1v;
                } else if constexpr (EPI == 5) {
                    ((float*)a.out0)[off] = val;
                } else {
                    ((float*)a.out0)[(size_t)bz * a.ld0 + off] = val;   // split-K partial
                }
                if (wtr_blk)
                    TL[(size_t)(col - n0) * TP + (row - m0)] = f2b(tv);
                if constexpr (GBS) gsum += tv;
            }
        }
    }

    if constexpr (GBS) {
        float s = gsum;
        s += __shfl_xor(s, 16);
        s += __shfl_xor(s, 32);
        if (lane < 16) atomicAdd(&gacc[wc * 16 + fr], s);
    }

    if (wtr_blk || GBS) {
        __syncthreads();
        if (wtr_blk) {
            for (int idx = tid; idx < 64 * 8; idx += 512) {
                int c = idx >> 3, ch = idx & 7;
                s16x8 v = *(const s16x8*)&TL[(size_t)c * TP + ch * 8];
                *(s16x8*)&a.outT[(size_t)(n0 - a.tc0 + c) * a.M + m0 + ch * 8] = v;
            }
        }
        if (GBS && tid < 64) atomicAdd(a.gbOut + n0 + tid, gacc[tid]);
    }
}

template<int EPI, bool WTR, bool GBS>
__global__ __launch_bounds__(512) void mgemm(GArgs a) {
    __shared__ __align__(16) unsigned short LB[LBSZ];
    __shared__ float gacc[128];
    mgemm_body<EPI, WTR, GBS>(LB, gacc, blockIdx.x, blockIdx.y, blockIdx.z,
                              gridDim.z, a, threadIdx.x);
}

// merged launch: path A = split-K grad GEMM (1088 blocks), path B = EPI4 dz1 (544)
__global__ __launch_bounds__(512) void mgemm_dual(GArgs a1, GArgs a2) {
    __shared__ __align__(16) unsigned short LB[LBSZ];
    __shared__ float gacc[128];
    int bid = blockIdx.x;
    if (bid < 1088) {
        int bz = bid >> 6, rem = bid & 63;
        mgemm_body<6, false, false>(LB, gacc, rem & 7, rem >> 3, bz, SPLITK, a1, threadIdx.x);
    } else {
        bid -= 1088;
        mgemm_body<4, true, true>(LB, gacc, bid & 7, bid >> 3, 0, 1, a2, threadIdx.x);
    }
}

// ---------------- mega setup: weight transposes + xm/lr rows + bias concat ----------------
struct TXP { const float* s[10]; unsigned short* d[10]; };
__global__ __launch_bounds__(256) void mega_setup(TXP p,
    const float* __restrict__ x, const float* __restrict__ meta, unsigned short* __restrict__ xm,
    const float* __restrict__ Wlr, const float* __restrict__ blr, float* __restrict__ w,
    const float* bq, const float* bk, const float* bv,
    const float* sb, float* cb1, float* cb2, float* gb)
{
    const int bid = blockIdx.x, tid = threadIdx.x;
    if (bid < 640) {                           // 10 x (8x8) weight transposes / copies
        __shared__ unsigned short t[64][65];
        int z = bid >> 6;
        const float* src = p.s[z];
        unsigned short* dst = p.d[z];
        int r0 = ((bid >> 3) & 7) * 64, c0 = (bid & 7) * 64;
        int lr = tid >> 4, lc = (tid & 15) * 4;
        if (z == 9) {                          // straight convert copy (W1 native)
#pragma unroll
            for (int rr = 0; rr < 64; rr += 16) {
                size_t base = (size_t)(r0 + lr + rr) * 512 + c0 + lc;
                float4 v = *(const float4*)(src + base);
                ushort4 o; o.x = f2b(v.x); o.y = f2b(v.y); o.z = f2b(v.z); o.w = f2b(v.w);
                *(ushort4*)(dst + base) = o;
            }
            return;
        }
#pragma unroll
        for (int rr = 0; rr < 64; rr += 16) {
            float4 v = *(const float4*)(src + (size_t)(r0 + lr + rr) * 512 + c0 + lc);
            t[lr + rr][lc] = f2b(v.x); t[lr + rr][lc + 1] = f2b(v.y);
            t[lr + rr][lc + 2] = f2b(v.z); t[lr + rr][lc + 3] = f2b(v.w);
        }
        __syncthreads();
#pragma unroll
        for (int cc = 0; cc < 64; cc += 16) {
            int c = lr + cc;
            ushort4 o; o.x = t[lc][c]; o.y = t[lc + 1][c]; o.z = t[lc + 2][c]; o.w = t[lc + 3][c];
            *(ushort4*)(dst + (size_t)(c0 + c) * 512 + r0 + lc) = o;
        }
        return;
    }
    if (bid < 640 + RROWS) {                   // one row: build xm (bf16) + adaptive lr (f32)
        __shared__ float sm[4];
        int row = bid - 640;
        int b = row / TTK, tt = row % TTK;
        const float* src = (tt < MM) ? meta + (size_t)tt * DD
                                     : x + ((size_t)b * SSQ + (tt - MM)) * DD;
        float x0 = src[tid], x1 = src[tid + 256];
        unsigned short* dst = xm + (size_t)row * DD;
        dst[tid] = f2b(x0); dst[tid + 256] = f2b(x1);
        float s = x0 * Wlr[tid] + x1 * Wlr[tid + 256];
        for (int o2 = 32; o2; o2 >>= 1) s += __shfl_down(s, o2);
        if ((tid & 63) == 0) sm[tid >> 6] = s;
        __syncthreads();
        if (tid == 0) w[row] = MAXALR_ / (1.f + __expf(-(sm[0] + sm[1] + sm[2] + sm[3] + blr[0])));
        return;
    }
    int i = (bid - 640 - RROWS) * 256 + tid;   // bias concat + zero gb
    if (i < 1536) {
        float v = (i < 512) ? bq[i] : (i < 1024) ? bk[i - 512] : bv[i - 1024];
        cb1[i] = v; cb2[i] = sb[i];
    } else if (i < 2560) {
        gb[i - 1536] = 0.f;
    }
}

// adamw fused into f32->bf16 transpose, summing SPLITK gradient partials;
// z==2 slice handles the two bias vectors
__global__ __launch_bounds__(256) void adamw_transp(const float* __restrict__ W,
                                                    const float* __restrict__ gWp,
                                                    unsigned short* __restrict__ dstBase,
                                                    const float* __restrict__ pb,
                                                    const float* __restrict__ gB,
                                                    float* __restrict__ bnOut) {
    if (blockIdx.z == 2) {
        int idx = (blockIdx.y * 8 + blockIdx.x) * 256 + threadIdx.x;
        if (idx < 2 * DD) {
            float gg = gB[idx];
            bnOut[idx] = pb[idx] * (1.f - LR_ * WD_) - LR_ * gg / (fabsf(gg) + EPS_);
        }
        return;
    }
    const int m = blockIdx.z;
    const float* src = W + (size_t)m * DD * DD;
    unsigned short* dst = dstBase + (size_t)m * DD * DD;
    __shared__ unsigned short t[64][65];
    int r0 = blockIdx.y * 64, c0 = blockIdx.x * 64;
    int lr = threadIdx.x >> 4, lc = (threadIdx.x & 15) * 4;
#pragma unroll
    for (int rr = 0; rr < 64; rr += 16) {
        size_t base = (size_t)(r0 + lr + rr) * 512 + c0 + lc;
        float4 v = *(const float4*)(src + base);
        float gx = 0.f, gy = 0.f, gz = 0.f, gw = 0.f;
        for (int z = 0; z < SPLITK; ++z) {
            const float4 p4 = *(const float4*)(gWp + ((size_t)z * 2 + m) * DD * DD + base);
            gx += p4.x; gy += p4.y; gz += p4.z; gw += p4.w;
        }
        t[lr + rr][lc]     = f2b(v.x * (1.f - LR_ * WD_) - LR_ * gx / (fabsf(gx) + EPS_));
        t[lr + rr][lc + 1] = f2b(v.y * (1.f - LR_ * WD_) - LR_ * gy / (fabsf(gy) + EPS_));
        t[lr + rr][lc + 2] = f2b(v.z * (1.f - LR_ * WD_) - LR_ * gz / (fabsf(gz) + EPS_));
        t[lr + rr][lc + 3] = f2b(v.w * (1.f - LR_ * WD_) - LR_ * gw / (fabsf(gw) + EPS_));
    }
    __syncthreads();
#pragma unroll
    for (int cc = 0; cc < 64; cc += 16) {
        int c = lr + cc;
        ushort4 o; o.x = t[lc][c]; o.y = t[lc + 1][c]; o.z = t[lc + 2][c]; o.w = t[lc + 3][c];
        *(ushort4*)(dst + (size_t)(c0 + c) * 512 + r0 + lc) = o;
    }
}

// ---------------- MFMA sliding-window attention ----------------
__global__ __launch_bounds__(256) void swa_mfma(const unsigned short* __restrict__ AQ,
                                                unsigned short* __restrict__ O) {
    __shared__ unsigned short Qs[64 * 64];     // XOR-swizzled (chunk ^= row&7)
    __shared__ unsigned short KP[192 * 64];    // K tile, then P tile (64x192)
    __shared__ unsigned short Vt[64 * VPAD];   // V transposed [d][j]

    const int tid = threadIdx.x;
    const int qt = blockIdx.x, h = blockIdx.y, b = blockIdx.z;
    const int i0 = MM + qt * 64;
    const int jbase = i0 - 128;
    const int r_ = tid >> 3, c_ = tid & 7;

#pragma unroll
    for (int rd = 0; rd < 2; ++rd) {
        int r = rd * 32 + r_;
        const unsigned short* src = AQ + ((size_t)(b * TTK + i0 + r)) * 1536 + h * HD
                                    + ((c_ ^ (r & 7)) * 8);
        gld16(src, &Qs[rd * 2048 + tid * 8]);
    }
#pragma unroll
    for (int rd = 0; rd < 6; ++rd) {
        int r = rd * 32 + r_;
        int j = jbase + r; if (j < 0) j = 0;
        const unsigned short* src = AQ + ((size_t)(b * TTK + j)) * 1536 + 512 + h * HD
                                    + ((c_ ^ (r & 7)) * 8);
        gld16(src, &KP[rd * 2048 + tid * 8]);
    }
#pragma unroll
    for (int rd = 0; rd < 6; ++rd) {
        int r = rd * 32 + r_;
        int j = jbase + r; if (j < 0) j = 0;
        const s16x8 vv = *(const s16x8*)(AQ + ((size_t)(b * TTK + j)) * 1536 + 1024 + h * HD + c_ * 8);
#pragma unroll
        for (int i = 0; i < 8; ++i)
            Vt[(c_ * 8 + i) * VPAD + r] = (unsigned short)vv[i];
    }
    __syncthreads();

    const int lane = tid & 63, w = tid >> 6;
    const int g = lane >> 4, fl = lane & 15;
    const int qA = w * 16 + fl;
    const int swzA = qA & 7;

    f32x4 sc[12];
#pragma unroll
    for (int t = 0; t < 12; ++t) { sc[t][0] = 0.f; sc[t][1] = 0.f; sc[t][2] = 0.f; sc[t][3] = 0.f; }

#pragma unroll
    for (int ks = 0; ks < 2; ++ks) {
        s16x8 af = *(const s16x8*)&Qs[qA * 64 + (((4 * ks + g) ^ swzA) * 8)];
#pragma unroll
        for (int t = 0; t < 12; ++t) {
            int jn = t * 16 + fl;
            s16x8 bf = *(const s16x8*)&KP[jn * 64 + (((4 * ks + g) ^ (jn & 7)) * 8)];
            sc[t] = __builtin_amdgcn_mfma_f32_16x16x32_bf16(af, bf, sc[t], 0, 0, 0);
        }
    }

    const int kmin = (i0 < 128) ? (128 - i0) : 0;
    float mx[4] = {-1e30f, -1e30f, -1e30f, -1e30f};
#pragma unroll
    for (int t = 0; t < 12; ++t) {
        int kk = t * 16 + fl;
#pragma unroll
        for (int r = 0; r < 4; ++r) {
            int qb = w * 16 + g * 4 + r;
            bool m = (kk > qb) && (kk <= qb + 128) && (kk >= kmin);
            float v = m ? sc[t][r] * 0.125f : -1e30f;
            sc[t][r] = v;
            mx[r] = fmaxf(mx[r], v);
        }
    }
#pragma unroll
    for (int r = 0; r < 4; ++r) {
        mx[r] = fmaxf(mx[r], __shfl_xor(mx[r], 1));
        mx[r] = fmaxf(mx[r], __shfl_xor(mx[r], 2));
        mx[r] = fmaxf(mx[r], __shfl_xor(mx[r], 4));
        mx[r] = fmaxf(mx[r], __shfl_xor(mx[r], 8));
    }
    float ls[4] = {0.f, 0.f, 0.f, 0.f};
#pragma unroll
    for (int t = 0; t < 12; ++t) {
#pragma unroll
        for (int r = 0; r < 4; ++r) {
            float p = __expf(sc[t][r] - mx[r]);
            sc[t][r] = p;
            ls[r] += p;
        }
    }
#pragma unroll
    for (int r = 0; r < 4; ++r) {
        ls[r] += __shfl_xor(ls[r], 1);
        ls[r] += __shfl_xor(ls[r], 2);
        ls[r] += __shfl_xor(ls[r], 4);
        ls[r] += __shfl_xor(ls[r], 8);
    }

    __syncthreads();

#pragma unroll
    for (int t = 0; t < 12; ++t) {
        int kk = t * 16 + fl;
#pragma unroll
        for (int r = 0; r < 4; ++r) {
            int qb = w * 16 + g * 4 + r;
            int ch = (kk >> 3) ^ (qb & 7);
            KP[qb * 192 + ch * 8 + (kk & 7)] = f2b(sc[t][r]);
        }
    }
    __syncthreads();

    f32x4 oacc[4];
#pragma unroll
    for (int dt = 0; dt < 4; ++dt) { oacc[dt][0] = 0.f; oacc[dt][1] = 0.f; oacc[dt][2] = 0.f; oacc[dt][3] = 0.f; }
#pragma unroll
    for (int js = 0; js < 6; ++js) {
        s16x8 pa = *(const s16x8*)&KP[qA * 192 + (((js * 4 + g) ^ swzA) * 8)];
#pragma unroll
        for (int dt = 0; dt < 4; ++dt) {
            s16x8 bv = *(const s16x8*)&Vt[(dt * 16 + fl) * VPAD + js * 32 + g * 8];
            oacc[dt] = __builtin_amdgcn_mfma_f32_16x16x32_bf16(pa, bv, oacc[dt], 0, 0, 0);
        }
    }

    float inv[4];
#pragma unroll
    for (int r = 0; r < 4; ++r) inv[r] = 1.f / ls[r];
#pragma unroll
    for (int dt = 0; dt < 4; ++dt) {
#pragma unroll
        for (int r = 0; r < 4; ++r) {
            int qb = w * 16 + g * 4 + r;
            int srow = qt * 64 + qb;
            int d = dt * 16 + fl;
            O[((size_t)b * SSQ + srow) * DD + h * HD + d] = f2b(oacc[dt][r] * inv[r]);
        }
    }
}

// ---------------- launch ----------------
extern "C" void kernel_launch(void* const* d_in, const int* in_sizes, int n_in,
                              void* d_out, int out_size, void* d_ws, size_t ws_size,
                              hipStream_t stream) {
    const float* x    = (const float*)d_in[0];
    const float* meta = (const float*)d_in[1];
    const float* lmmW = (const float*)d_in[2];
    const float* lmmb = (const float*)d_in[3];
    const float* Wq   = (const float*)d_in[4];
    const float* bq   = (const float*)d_in[5];
    const float* Wk   = (const float*)d_in[6];
    const float* bk   = (const float*)d_in[7];
    const float* Wv   = (const float*)d_in[8];
    const float* bv   = (const float*)d_in[9];
    const float* Wlr  = (const float*)d_in[10];
    const float* blr  = (const float*)d_in[11];
    const float* swaW = (const float*)d_in[12];
    const float* swab = (const float*)d_in[13];
    float* out = (float*)d_out;
    (void)in_sizes; (void)n_in; (void)out_size; (void)ws_size;

    char* wsb = (char*)d_ws;
    size_t off = 0;
    auto alloc = [&](size_t bytes) -> void* {
        void* p = wsb + off; off = (off + bytes + 255) & ~(size_t)255; return p;
    };
    const size_t BIGE = (size_t)RROWS * DD;
    unsigned short* qkv  = (unsigned short*)alloc((size_t)RROWS * 1536 * 2);  // q|k|v, later aq|ak|av
    unsigned short* xm   = (unsigned short*)alloc(BIGE * 2);
    unsigned short* h1   = (unsigned short*)alloc(BIGE * 2);
    unsigned short* z1   = (unsigned short*)alloc(BIGE * 2);
    unsigned short* d2   = (unsigned short*)alloc(BIGE * 2);
    unsigned short* dz2  = (unsigned short*)alloc(BIGE * 2);
    unsigned short* dz1  = (unsigned short*)alloc(BIGE * 2);
    unsigned short* h1r  = (unsigned short*)alloc(BIGE * 2);
    unsigned short* retr = (unsigned short*)alloc(BIGE * 2);
    unsigned short* o    = (unsigned short*)alloc((size_t)OROWS * DD * 2);
    unsigned short* kT   = (unsigned short*)alloc(BIGE * 2);
    unsigned short* h1T  = (unsigned short*)alloc(BIGE * 2);
    unsigned short* dz2T = (unsigned short*)alloc(BIGE * 2);
    unsigned short* dz1T = (unsigned short*)alloc(BIGE * 2);
    unsigned short* Wt   = (unsigned short*)alloc((size_t)12 * DD * DD * 2);
    float* gWp  = (float*)alloc((size_t)SPLITK * 2 * DD * DD * 4);   // split-K partials
    float* w    = (float*)alloc((size_t)RROWS * 4);
    float* gb   = (float*)alloc(1024 * 4);
    float* bn   = (float*)alloc(1024 * 4);
    float* cbQ  = (float*)alloc(1536 * 4);
    float* cbS  = (float*)alloc(1536 * 4);
    auto WT = [&](int i) { return Wt + (size_t)i * DD * DD; };
    // slots: 0-2 Wq/Wk/Wv^T | 3 W0^T | 4 W1^T | 5-8 swa0-3^T | 9 W1 native | 10-11 updated W^T

    TXP tp{};
    tp.s[0] = Wq;             tp.d[0] = WT(0);
    tp.s[1] = Wk;             tp.d[1] = WT(1);
    tp.s[2] = Wv;             tp.d[2] = WT(2);
    tp.s[3] = lmmW;           tp.d[3] = WT(3);
    tp.s[4] = lmmW + DD * DD; tp.d[4] = WT(4);
    tp.s[5] = swaW + 0 * DD * DD; tp.d[5] = WT(5);
    tp.s[6] = swaW + 1 * DD * DD; tp.d[6] = WT(6);
    tp.s[7] = swaW + 2 * DD * DD; tp.d[7] = WT(7);
    tp.s[8] = swaW + 3 * DD * DD; tp.d[8] = WT(8);
    tp.s[9] = lmmW + DD * DD; tp.d[9] = WT(9);   // straight copy (W1 native)
    mega_setup<<<640 + RROWS + 10, 256, 0, stream>>>(tp, x, meta, xm, Wlr, blr, w,
                                                     bq, bk, bv, swab, cbQ, cbS, gb);

    auto ga = [](const unsigned short* A, const unsigned short* Bm, const float* bias,
                 const unsigned short* a0, const unsigned short* a1, const float* wr,
                 void* o0, unsigned short* o1, unsigned short* oT, int t0, int t1, float* gbo,
                 int M, int N, int K, int lda, int l0, int l1) {
        GArgs g{A, Bm, bias, a0, a1, wr, o0, o1, oT, t0, t1, gbo, M, N, K, lda, l0, l1};
        return g;
    };
    const dim3 gB(512);

    // fused q|k|v projection (writes kT via LDS bounce)
    mgemm<0, true, false><<<dim3(24, 68), gB, 0, stream>>>(
        ga(xm, WT(0), cbQ, nullptr, nullptr, nullptr, qkv, nullptr, kT, 512, 1024, nullptr,
           RROWS, 1536, DD, DD, 0, 0));

    // lmm forward on k (h1 + h1T + z1), then fused pred/d2/dz2 (+dz2T +gb1)
    mgemm<2, true, false><<<dim3(8, 68), gB, 0, stream>>>(
        ga(qkv + 512, WT(3), lmmb, qkv + 512, nullptr, nullptr, h1, z1, h1T, 0, 512, nullptr,
           RROWS, DD, DD, 1536, 1536, 0));
    mgemm<3, true, true><<<dim3(8, 68), gB, 0, stream>>>(
        ga(h1, WT(4), lmmb + DD, h1, qkv + 1024, w, d2, dz2, dz2T, 0, 512, gb + DD,
           RROWS, DD, DD, DD, DD, 1536));

    // gW1 grad (split-K partials) MERGED with dh1/dz1 (independent)
    mgemm_dual<<<1632, gB, 0, stream>>>(
        ga(h1T, dz2T, nullptr, nullptr, nullptr, nullptr, gWp + DD * DD, nullptr, nullptr, 0, 0, nullptr,
           DD, DD, RROWS, RROWS, 2 * DD * DD, 0),
        ga(dz2, WT(9), nullptr, d2, z1, nullptr, dz1, nullptr, dz1T, 0, 512, gb,
           RROWS, DD, DD, DD, DD, DD));

    // gW0 grad (split-K partials)
    mgemm<6, false, false><<<dim3(8, 8, SPLITK), gB, 0, stream>>>(
        ga(kT, dz1T, nullptr, nullptr, nullptr, nullptr, gWp, nullptr, nullptr, 0, 0, nullptr,
           DD, DD, RROWS, RROWS, 2 * DD * DD, 0));

    // AdamW (weights: partial-sum + update + transpose; biases in z==2 slice)
    adamw_transp<<<dim3(8, 8, 3), 256, 0, stream>>>(lmmW, gWp, WT(10), lmmb, gb, bn);

    // retrieval with updated memory
    mgemm<1, false, false><<<dim3(8, 68), gB, 0, stream>>>(
        ga(qkv, WT(10), bn, qkv, nullptr, nullptr, h1r, nullptr, nullptr, 0, 0, nullptr,
           RROWS, DD, DD, 1536, 1536, 0));
    mgemm<1, false, false><<<dim3(8, 68), gB, 0, stream>>>(
        ga(h1r, WT(11), bn + DD, h1r, nullptr, nullptr, retr, nullptr, nullptr, 0, 0, nullptr,
           RROWS, DD, DD, DD, DD, 0));

    // fused SWA projections, MFMA attention, out-proj
    mgemm<0, false, false><<<dim3(24, 68), gB, 0, stream>>>(
        ga(retr, WT(5), cbS, nullptr, nullptr, nullptr, qkv, nullptr, nullptr, 0, 0, nullptr,
           RROWS, 1536, DD, DD, 0, 0));
    swa_mfma<<<dim3(16, 8, 4), 256, 0, stream>>>(qkv, o);
    mgemm<5, false, false><<<dim3(8, 64), gB, 0, stream>>>(
        ga(o, WT(8), swab + 3 * DD, nullptr, nullptr, nullptr, out, nullptr, nullptr, 0, 0, nullptr,
           OROWS, DD, DD, DD, 0, 0));
}